// Round 3
// baseline (25669.781 us; speedup 1.0000x reference)
//
#include <hip/hip_runtime.h>

// Problem constants (AF2SmilesTransformer)
constexpr int N_B = 32, N_S = 200, N_M = 256, N_D = 1024, N_H = 16;
constexpr int N_F = 2048, N_L = 16, N_V = 128, N_DH = 64, N_DEMB = 384;

typedef short short8 __attribute__((ext_vector_type(8)));
typedef short short4v __attribute__((ext_vector_type(4)));
typedef float f32x4 __attribute__((ext_vector_type(4)));

// ---------------- bf16 helpers (round-to-nearest-even) ----------------
__device__ __forceinline__ unsigned short f2bf(float x) {
  unsigned u = __float_as_uint(x);
  u += 0x7fffu + ((u >> 16) & 1u);
  return (unsigned short)(u >> 16);
}
__device__ __forceinline__ float bf2f(unsigned short h) {
  return __uint_as_float(((unsigned)h) << 16);
}
__device__ __forceinline__ void hilo4(const float* v, short4v& hi, short4v& lo) {
#pragma unroll
  for (int j = 0; j < 4; ++j) {
    unsigned short hb = f2bf(v[j]);
    hi[j] = (short)hb;
    lo[j] = (short)f2bf(v[j] - bf2f(hb));
  }
}

// async global->LDS 16B copy
__device__ __forceinline__ void load_lds16(const void* g, void* l) {
  __builtin_amdgcn_global_load_lds(
      (const __attribute__((address_space(1))) unsigned int*)g,
      (__attribute__((address_space(3))) unsigned int*)l, 16, 0, 0);
}

// ---------------------------------------------------------------------------
// Embedding: h = tok_emb[x] + pos_emb[x]  (pos indexed by TOKEN id — faithful)
// EB=1 additionally writes bf16 hi/lo planes of h.
// ---------------------------------------------------------------------------
template<int EB>
__global__ __launch_bounds__(256) void embed_kernel(
    const int* __restrict__ x, const float* __restrict__ tok,
    const float* __restrict__ pos, float* __restrict__ h,
    short* __restrict__ hhi, short* __restrict__ hlo) {
  const int row = blockIdx.x;
  const int tid = x[row];
  const float4* te = (const float4*)(tok + (size_t)tid * N_D);
  const float4* pe = (const float4*)(pos + (size_t)tid * N_D);
  float4* out = (float4*)(h + (size_t)row * N_D);
  const int i = threadIdx.x;
  const float4 a = te[i], b = pe[i];
  const float4 o = make_float4(a.x + b.x, a.y + b.y, a.z + b.z, a.w + b.w);
  out[i] = o;
  if (EB) {
    float v[4] = {o.x, o.y, o.z, o.w};
    short4v hi, lo;
    hilo4(v, hi, lo);
    *(short4v*)(hhi + (size_t)row * N_D + i * 4) = hi;
    *(short4v*)(hlo + (size_t)row * N_D + i * 4) = lo;
  }
}

// ---------------------------------------------------------------------------
// bf16x3 split MFMA GEMM.  C[M,N] = act(Af32 @ Wf32 + bias) computed as
// Ah·Bh + Al·Bh + Ah·Bl with bf16 hi/lo planes (error ~2^-16 relative).
// A planes: [Mrows][K] bf16 row-major.  B planes: W^T [N][K] bf16 row-major.
// 128x128 tile, BK=64, 256 thr (4 waves 2x2, each 64x64 = 4x4 frags 16x16x32).
// LDS linear (global_load_lds requirement); bank-decorrelation via XOR
// preswizzle of the SOURCE k-block (b ^ (row&7)) + matching XOR on ds_read.
// Verified by hand: LDS[row][b] = global[row][b^(row&7)]; frag read for
// global k-block (q*4+g) of row (c) reads position ((q*4+g)^c)&7.
// Requires M%128==0, N%128==0, K%64==0.
// ---------------------------------------------------------------------------
template<int ACT, int BIAS, int EMIT>  // ACT: relu; EMIT: 0=f32 C, 1=bf16 hi/lo C
__global__ __launch_bounds__(256, 2) void gemm_bf(
    const short* __restrict__ Ahi, const short* __restrict__ Alo,
    const short* __restrict__ Bhi, const short* __restrict__ Blo,
    const float* __restrict__ bias, float* __restrict__ Cf,
    short* __restrict__ Chi, short* __restrict__ Clo,
    const int K, const int Ncols) {
  __shared__ short lds[4][8192];  // planes: Ahi, Alo, Bhi, Blo (16KB each)
  const int t = threadIdx.x;
  const int bm0 = blockIdx.x * 128, bn0 = blockIdx.y * 128;
  const int w = t >> 6, l = t & 63;
  const int wm = (w >> 1) * 64, wn = (w & 1) * 64;
  const int c = l & 15, g = l >> 4;

  f32x4 acc[4][4] = {};

  // staging: chunk cc: LDS row = cc*32 + (t>>3), stored 16B-block = t&7,
  // holding global k-block (t&7) ^ (row&7).
  const int srow = t >> 3;
  const int sblk = (t & 7) ^ (srow & 7);
  const long arow0 = (long)(bm0 + srow) * K + sblk * 8;
  const long brow0 = (long)(bn0 + srow) * K + sblk * 8;

  // frag-read byte offsets within a row: position ((q*4+g) ^ c) & 7
  const int oq0 = ((g ^ c) & 7) * 16;
  const int oq1 = (((4 + g) ^ c) & 7) * 16;
  const int arow = (wm + c) * 128;  // row stride = 64 shorts = 128 B
  const int brow = (wn + c) * 128;

  for (int k0 = 0; k0 < K; k0 += 64) {
#pragma unroll
    for (int cc = 0; cc < 4; ++cc) {
      const long asrc = arow0 + (long)cc * 32 * K + k0;
      const long bsrc = brow0 + (long)cc * 32 * K + k0;
      short* ldst = &lds[0][(cc * 256 + t) * 8];
      load_lds16(Ahi + asrc, ldst);
      load_lds16(Alo + asrc, ldst + 8192);
      load_lds16(Bhi + bsrc, ldst + 16384);
      load_lds16(Blo + bsrc, ldst + 24576);
    }
    __syncthreads();
#pragma unroll
    for (int q = 0; q < 2; ++q) {
      const int oq = q ? oq1 : oq0;
      short8 ah[4], al[4], bh[4], bl[4];
#pragma unroll
      for (int i = 0; i < 4; ++i) {
        ah[i] = *(const short8*)((const char*)&lds[0][0] + arow + i * 2048 + oq);
        al[i] = *(const short8*)((const char*)&lds[1][0] + arow + i * 2048 + oq);
        bh[i] = *(const short8*)((const char*)&lds[2][0] + brow + i * 2048 + oq);
        bl[i] = *(const short8*)((const char*)&lds[3][0] + brow + i * 2048 + oq);
      }
#pragma unroll
      for (int i = 0; i < 4; ++i)
#pragma unroll
        for (int j = 0; j < 4; ++j) {
          acc[i][j] = __builtin_amdgcn_mfma_f32_16x16x32_bf16(ah[i], bh[j], acc[i][j], 0, 0, 0);
          acc[i][j] = __builtin_amdgcn_mfma_f32_16x16x32_bf16(al[i], bh[j], acc[i][j], 0, 0, 0);
          acc[i][j] = __builtin_amdgcn_mfma_f32_16x16x32_bf16(ah[i], bl[j], acc[i][j], 0, 0, 0);
        }
    }
    __syncthreads();
  }

  float bj[4] = {0.f, 0.f, 0.f, 0.f};
  if (BIAS) {
#pragma unroll
    for (int j = 0; j < 4; ++j) bj[j] = bias[bn0 + wn + j * 16 + c];
  }
  // C/D layout (m89-verified): col = lane&15, row = (lane>>4)*4 + reg
#pragma unroll
  for (int i = 0; i < 4; ++i) {
    const int row = bm0 + wm + i * 16 + g * 4;
#pragma unroll
    for (int j = 0; j < 4; ++j) {
      const int col = bn0 + wn + j * 16 + c;
#pragma unroll
      for (int r = 0; r < 4; ++r) {
        float v = acc[i][j][r] + bj[j];
        if (ACT == 1) v = fmaxf(v, 0.f);
        const long o = (long)(row + r) * Ncols + col;
        if (EMIT == 0) {
          Cf[o] = v;
        } else {
          const unsigned short hb = f2bf(v);
          Chi[o] = (short)hb;
          Clo[o] = (short)f2bf(v - bf2f(hb));
        }
      }
    }
  }
}

// ---------------------------------------------------------------------------
// Weight transpose + hi/lo convert: W [Kd][Nd] f32 -> Wt_hi/lo [Nd][Kd] bf16.
// wconv_one: one 64x64 tile per block (used for proj_w only).
// wconv_layer: ALL 10 matrices of one layer in a single 3072-block dispatch.
// ---------------------------------------------------------------------------
__device__ __forceinline__ void wconv_tile(
    const float* __restrict__ src, short* __restrict__ dh,
    short* __restrict__ dl, const int Kd, const int Nd,
    const int k0, const int n0, const int t) {
  __shared__ float T[64][65];
#pragma unroll
  for (int i2 = 0; i2 < 4; ++i2) {
    const int id = t + i2 * 256;
    const int kr = id >> 4, nq = (id & 15) * 4;
    const float4 v = *(const float4*)(src + (long)(k0 + kr) * Nd + n0 + nq);
    T[kr][nq] = v.x; T[kr][nq + 1] = v.y; T[kr][nq + 2] = v.z; T[kr][nq + 3] = v.w;
  }
  __syncthreads();
  const int n = t >> 2, kb2 = (t & 3) * 16;
  const long obase = (long)(n0 + n) * Kd + k0 + kb2;
  short8 h0, h1, l0, l1;
#pragma unroll
  for (int i = 0; i < 8; ++i) {
    float xv = T[kb2 + i][n];
    unsigned short hb = f2bf(xv);
    h0[i] = (short)hb; l0[i] = (short)f2bf(xv - bf2f(hb));
  }
#pragma unroll
  for (int i = 0; i < 8; ++i) {
    float xv = T[kb2 + 8 + i][n];
    unsigned short hb = f2bf(xv);
    h1[i] = (short)hb; l1[i] = (short)f2bf(xv - bf2f(hb));
  }
  *(short8*)(dh + obase) = h0;
  *(short8*)(dh + obase + 8) = h1;
  *(short8*)(dl + obase) = l0;
  *(short8*)(dl + obase + 8) = l1;
}

__global__ __launch_bounds__(256) void wconv_one(
    const float* __restrict__ src, short* __restrict__ whi,
    short* __restrict__ wlo, const int Kd, const int Nd) {
  const int ntn = Nd >> 6;
  const int tk = blockIdx.x / ntn, tn = blockIdx.x % ntn;
  wconv_tile(src, whi, wlo, Kd, Nd, tk * 64, tn * 64, threadIdx.x);
}

__global__ __launch_bounds__(256) void wconv_layer(
    const float* __restrict__ w0, const float* __restrict__ w1,
    const float* __restrict__ w2, const float* __restrict__ w3,
    const float* __restrict__ w4, const float* __restrict__ w5,
    const float* __restrict__ w6, const float* __restrict__ w7,
    const float* __restrict__ f1, const float* __restrict__ f2,
    short* __restrict__ whi, short* __restrict__ wlo) {
  const int bid = blockIdx.x;
  const float* src;
  short *dh, *dl;
  int Kd, Nd, tile, nlog;
  if (bid < 2048) {                         // 8x [1024][1024]
    const int m = bid >> 8;
    tile = bid & 255; Kd = 1024; Nd = 1024; nlog = 4;
    switch (m) {
      case 0: src = w0; break; case 1: src = w1; break;
      case 2: src = w2; break; case 3: src = w3; break;
      case 4: src = w4; break; case 5: src = w5; break;
      case 6: src = w6; break; default: src = w7; break;
    }
    dh = whi + (long)m * 1048576; dl = wlo + (long)m * 1048576;
  } else if (bid < 2560) {                  // ffn_w1 [1024][2048]
    tile = bid - 2048; Kd = 1024; Nd = 2048; nlog = 5;
    src = f1; dh = whi + 8388608; dl = wlo + 8388608;
  } else {                                  // ffn_w2 [2048][1024]
    tile = bid - 2560; Kd = 2048; Nd = 1024; nlog = 4;
    src = f2; dh = whi + 10485760; dl = wlo + 10485760;
  }
  const int tk = tile >> nlog, tn = tile & ((1 << nlog) - 1);
  wconv_tile(src, dh, dl, Kd, Nd, tk * 64, tn * 64, threadIdx.x);
}

// elementwise f32 -> bf16 hi/lo (af_emb)
__global__ __launch_bounds__(256) void aconv(
    const float* __restrict__ in, short* __restrict__ hi, short* __restrict__ lo) {
  const long i = (long)blockIdx.x * 256 + threadIdx.x;
  const float4 v4 = ((const float4*)in)[i];
  float v[4] = {v4.x, v4.y, v4.z, v4.w};
  short4v h, l;
  hilo4(v, h, l);
  *(short4v*)(hi + i * 4) = h;
  *(short4v*)(lo + i * 4) = l;
}

// ---------------------------------------------------------------------------
// fp32 vector SGEMM (fallback path) — 128x128 tile, 8x8 micro-tile
// ---------------------------------------------------------------------------
template<int ACT, bool BIAS>
__global__ __launch_bounds__(256) void gemm128(
    const float* __restrict__ A, const float* __restrict__ Bw,
    const float* __restrict__ bias, float* __restrict__ C,
    const int Mdim, const int Ndim, const int Kdim) {
  __shared__ float As[16][132];
  __shared__ float Bs[16][132];
  const int t = threadIdx.x;
  const int bm0 = blockIdx.x * 128, bn0 = blockIdx.y * 128;
  const int tx4 = (t & 15) * 4, ty4 = (t >> 4) * 4;
  float acc[8][8];
#pragma unroll
  for (int i = 0; i < 8; ++i)
#pragma unroll
    for (int j = 0; j < 8; ++j) acc[i][j] = 0.f;
  const int ar = t >> 2, ac = (t & 3) * 4;
  const int br = t >> 5, bc = (t & 31) * 4;
  for (int k0 = 0; k0 < Kdim; k0 += 16) {
#pragma unroll
    for (int i = 0; i < 2; ++i) {
      const float4 v = *(const float4*)(A + (size_t)(bm0 + ar + i * 64) * Kdim + k0 + ac);
      As[ac + 0][ar + i * 64] = v.x; As[ac + 1][ar + i * 64] = v.y;
      As[ac + 2][ar + i * 64] = v.z; As[ac + 3][ar + i * 64] = v.w;
    }
#pragma unroll
    for (int i = 0; i < 2; ++i)
      *(float4*)&Bs[br + i * 8][bc] =
          *(const float4*)(Bw + (size_t)(k0 + br + i * 8) * Ndim + bn0 + bc);
    __syncthreads();
#pragma unroll
    for (int kk = 0; kk < 16; ++kk) {
      const float4 a0 = *(const float4*)&As[kk][ty4];
      const float4 a1 = *(const float4*)&As[kk][64 + ty4];
      const float4 b0 = *(const float4*)&Bs[kk][tx4];
      const float4 b1 = *(const float4*)&Bs[kk][64 + tx4];
      const float ra[8] = {a0.x, a0.y, a0.z, a0.w, a1.x, a1.y, a1.z, a1.w};
      const float rb[8] = {b0.x, b0.y, b0.z, b0.w, b1.x, b1.y, b1.z, b1.w};
#pragma unroll
      for (int i = 0; i < 8; ++i)
#pragma unroll
        for (int j = 0; j < 8; ++j) acc[i][j] = fmaf(ra[i], rb[j], acc[i][j]);
    }
    __syncthreads();
  }
  float4 bs0 = make_float4(0, 0, 0, 0), bs1 = make_float4(0, 0, 0, 0);
  if (BIAS) {
    bs0 = *(const float4*)(bias + bn0 + tx4);
    bs1 = *(const float4*)(bias + bn0 + 64 + tx4);
  }
#pragma unroll
  for (int i = 0; i < 8; ++i) {
    const int row = bm0 + ((i < 4) ? (ty4 + i) : (64 + ty4 + i - 4));
    float4 o0 = make_float4(acc[i][0] + bs0.x, acc[i][1] + bs0.y,
                            acc[i][2] + bs0.z, acc[i][3] + bs0.w);
    float4 o1 = make_float4(acc[i][4] + bs1.x, acc[i][5] + bs1.y,
                            acc[i][6] + bs1.z, acc[i][7] + bs1.w);
    if (ACT == 1) {
      o0.x = fmaxf(o0.x, 0.f); o0.y = fmaxf(o0.y, 0.f);
      o0.z = fmaxf(o0.z, 0.f); o0.w = fmaxf(o0.w, 0.f);
      o1.x = fmaxf(o1.x, 0.f); o1.y = fmaxf(o1.y, 0.f);
      o1.z = fmaxf(o1.z, 0.f); o1.w = fmaxf(o1.w, 0.f);
    }
    *(float4*)(C + (size_t)row * Ndim + bn0 + tx4) = o0;
    *(float4*)(C + (size_t)row * Ndim + bn0 + 64 + tx4) = o1;
  }
}

// 64x64 fp32 tile for the narrow logits GEMM (N=128)
template<int ACT, bool BIAS>
__global__ __launch_bounds__(256) void gemm64(
    const float* __restrict__ A, const float* __restrict__ Bw,
    const float* __restrict__ bias, float* __restrict__ C,
    const int Mdim, const int Ndim, const int Kdim) {
  __shared__ float As[16][68];
  __shared__ float Bs[16][68];
  const int t = threadIdx.x;
  const int bm0 = blockIdx.x * 64, bn0 = blockIdx.y * 64;
  const int tx4 = (t & 15) * 4, ty4 = (t >> 4) * 4;
  float acc[4][4];
#pragma unroll
  for (int i = 0; i < 4; ++i)
#pragma unroll
    for (int j = 0; j < 4; ++j) acc[i][j] = 0.f;
  const int ar = t >> 2, ac = (t & 3) * 4;
  const int br = t >> 4, bc = (t & 15) * 4;
  for (int k0 = 0; k0 < Kdim; k0 += 16) {
    const float4 v = *(const float4*)(A + (size_t)(bm0 + ar) * Kdim + k0 + ac);
    As[ac + 0][ar] = v.x; As[ac + 1][ar] = v.y;
    As[ac + 2][ar] = v.z; As[ac + 3][ar] = v.w;
    *(float4*)&Bs[br][bc] = *(const float4*)(Bw + (size_t)(k0 + br) * Ndim + bn0 + bc);
    __syncthreads();
#pragma unroll
    for (int kk = 0; kk < 16; ++kk) {
      const float4 a0 = *(const float4*)&As[kk][ty4];
      const float4 b0 = *(const float4*)&Bs[kk][tx4];
      const float ra[4] = {a0.x, a0.y, a0.z, a0.w};
      const float rb[4] = {b0.x, b0.y, b0.z, b0.w};
#pragma unroll
      for (int i = 0; i < 4; ++i)
#pragma unroll
        for (int j = 0; j < 4; ++j) acc[i][j] = fmaf(ra[i], rb[j], acc[i][j]);
    }
    __syncthreads();
  }
  float4 bs0 = make_float4(0, 0, 0, 0);
  if (BIAS) bs0 = *(const float4*)(bias + bn0 + tx4);
#pragma unroll
  for (int i = 0; i < 4; ++i) {
    float4 o0 = make_float4(acc[i][0] + bs0.x, acc[i][1] + bs0.y,
                            acc[i][2] + bs0.z, acc[i][3] + bs0.w);
    if (ACT == 1) {
      o0.x = fmaxf(o0.x, 0.f); o0.y = fmaxf(o0.y, 0.f);
      o0.z = fmaxf(o0.z, 0.f); o0.w = fmaxf(o0.w, 0.f);
    }
    *(float4*)(C + (size_t)(bm0 + ty4 + i) * Ndim + bn0 + tx4) = o0;
  }
}

// ---------------------------------------------------------------------------
// Attention (fp32 vector). One block = (b, h, 32-q-row tile).
// qStr/kvStr: row strides of the Q and K/V buffers (fused-QKV support).
// EB=1: epilogue emits bf16 hi/lo output planes (stride N_D) instead of f32.
// NOTE: full K-range is computed on purpose — the reference's additive -1e9
// mask means fully-masked rows reduce to softmax(raw) over ALL keys; any
// causal truncation would diverge on those rows.
// ---------------------------------------------------------------------------
template<bool SELF, int EB>
__global__ __launch_bounds__(256) void attn_kernel(
    const float* __restrict__ Qb, const float* __restrict__ Kb,
    const float* __restrict__ Vb, const int* __restrict__ xids,
    float* __restrict__ Ob, short* __restrict__ Ohi, short* __restrict__ Olo,
    const int Sk, const int qStr, const int kvStr) {
  __shared__ float Qs[32][N_DH + 4];
  __shared__ float KV[64][N_DH + 4];
  __shared__ float Sbuf[32][N_M + 8];
  const int t = threadIdx.x;
  const int q0 = blockIdx.x * 32;
  const int hh = blockIdx.y, b = blockIdx.z;
  const float* Qp = Qb + (size_t)b * N_S * qStr + hh * N_DH;
  const float* Kp = Kb + (size_t)b * Sk * kvStr + hh * N_DH;
  const float* Vp = Vb + (size_t)b * Sk * kvStr + hh * N_DH;

#pragma unroll
  for (int i = 0; i < 2; ++i) {
    const int idx = t + i * 256;
    const int r = idx >> 4, c = (idx & 15) * 4;
    float4 v = make_float4(0, 0, 0, 0);
    if (q0 + r < N_S) v = *(const float4*)(Qp + (size_t)(q0 + r) * qStr + c);
    Qs[r][c] = v.x; Qs[r][c + 1] = v.y; Qs[r][c + 2] = v.z; Qs[r][c + 3] = v.w;
  }

  const int rp = t >> 4;
  const int kq = (t & 15) * 4;
  const int qiA = rp * 2, qiB = rp * 2 + 1;

  for (int kc = 0; kc < Sk; kc += 64) {
    __syncthreads();
#pragma unroll
    for (int i = 0; i < 4; ++i) {
      const int idx = t + i * 256;
      const int r = idx >> 4, c = (idx & 15) * 4;
      float4 v = make_float4(0, 0, 0, 0);
      if (kc + r < Sk) v = *(const float4*)(Kp + (size_t)(kc + r) * kvStr + c);
      KV[c + 0][r] = v.x; KV[c + 1][r] = v.y; KV[c + 2][r] = v.z; KV[c + 3][r] = v.w;
    }
    __syncthreads();
    float accA[4] = {0, 0, 0, 0}, accB[4] = {0, 0, 0, 0};
#pragma unroll
    for (int d = 0; d < N_DH; d += 4) {
      const float4 qa = *(const float4*)&Qs[qiA][d];
      const float4 qb4 = *(const float4*)&Qs[qiB][d];
      const float qaA[4] = {qa.x, qa.y, qa.z, qa.w};
      const float qaB[4] = {qb4.x, qb4.y, qb4.z, qb4.w};
#pragma unroll
      for (int dd = 0; dd < 4; ++dd) {
        const float4 kv = *(const float4*)&KV[d + dd][kq];
        const float kva[4] = {kv.x, kv.y, kv.z, kv.w};
#pragma unroll
        for (int j = 0; j < 4; ++j) {
          accA[j] = fmaf(qaA[dd], kva[j], accA[j]);
          accB[j] = fmaf(qaB[dd], kva[j], accB[j]);
        }
      }
    }
#pragma unroll
    for (int j = 0; j < 4; ++j) {
      const int kg = kc + kq + j;
      if (kg < Sk) {
        float sA = accA[j] * 0.125f;
        float sB = accB[j] * 0.125f;
        if (SELF) {
          const bool kvld = (xids[b * N_S + kg] != 0);
          if (!(kvld && (kg <= q0 + qiA))) sA -= 1e9f;
          if (!(kvld && (kg <= q0 + qiB))) sB -= 1e9f;
        }
        Sbuf[qiA][kg] = sA;
        Sbuf[qiB][kg] = sB;
      }
    }
  }

  __syncthreads();
  {
    const int row = t >> 3, sub = t & 7;
    if (q0 + row < N_S) {
      float m = -3.0e38f;
      for (int cc = sub; cc < Sk; cc += 8) m = fmaxf(m, Sbuf[row][cc]);
#pragma unroll
      for (int off = 1; off < 8; off <<= 1) m = fmaxf(m, __shfl_xor(m, off));
      float e = 0.f;
      for (int cc = sub; cc < Sk; cc += 8) {
        const float p = __expf(Sbuf[row][cc] - m);
        Sbuf[row][cc] = p;
        e += p;
      }
#pragma unroll
      for (int off = 1; off < 8; off <<= 1) e += __shfl_xor(e, off);
      const float inv = 1.f / e;
      for (int cc = sub; cc < Sk; cc += 8) Sbuf[row][cc] *= inv;
    }
  }

  float oA[4] = {0, 0, 0, 0}, oB[4] = {0, 0, 0, 0};
  for (int kc = 0; kc < Sk; kc += 64) {
    __syncthreads();
#pragma unroll
    for (int i = 0; i < 4; ++i) {
      const int idx = t + i * 256;
      const int r = idx >> 4, c = (idx & 15) * 4;
      float4 v = make_float4(0, 0, 0, 0);
      if (kc + r < Sk) v = *(const float4*)(Vp + (size_t)(kc + r) * kvStr + c);
      *(float4*)&KV[r][c] = v;
    }
    __syncthreads();
    const int klim = (Sk - kc < 64) ? (Sk - kc) : 64;
    for (int k4 = 0; k4 < klim; k4 += 4) {
      const float4 pA4 = *(const float4*)&Sbuf[qiA][kc + k4];
      const float4 pB4 = *(const float4*)&Sbuf[qiB][kc + k4];
      const float pA[4] = {pA4.x, pA4.y, pA4.z, pA4.w};
      const float pB[4] = {pB4.x, pB4.y, pB4.z, pB4.w};
#pragma unroll
      for (int kk = 0; kk < 4; ++kk) {
        const float4 vv = *(const float4*)&KV[k4 + kk][kq];
        const float vva[4] = {vv.x, vv.y, vv.z, vv.w};
#pragma unroll
        for (int j = 0; j < 4; ++j) {
          oA[j] = fmaf(pA[kk], vva[j], oA[j]);
          oB[j] = fmaf(pB[kk], vva[j], oB[j]);
        }
      }
    }
  }
  if (q0 + qiA < N_S) {
    const size_t base = (size_t)(b * N_S + q0 + qiA) * N_D + hh * N_DH + kq;
    if (EB) {
      short4v hi, lo; hilo4(oA, hi, lo);
      *(short4v*)(Ohi + base) = hi; *(short4v*)(Olo + base) = lo;
    } else {
      *(float4*)(Ob + base) = make_float4(oA[0], oA[1], oA[2], oA[3]);
    }
  }
  if (q0 + qiB < N_S) {
    const size_t base = (size_t)(b * N_S + q0 + qiB) * N_D + hh * N_DH + kq;
    if (EB) {
      short4v hi, lo; hilo4(oB, hi, lo);
      *(short4v*)(Ohi + base) = hi; *(short4v*)(Olo + base) = lo;
    } else {
      *(float4*)(Ob + base) = make_float4(oB[0], oB[1], oB[2], oB[3]);
    }
  }
}

// ---------------------------------------------------------------------------
// Fused residual + LayerNorm (in place): h = LN(h + delta)*g + b
// EB=1: also write bf16 hi/lo planes of the result.
// ---------------------------------------------------------------------------
template<int EB>
__global__ __launch_bounds__(256) void resln_kernel(
    float* __restrict__ h, const float* __restrict__ dlt,
    const float* __restrict__ g, const float* __restrict__ bt,
    short* __restrict__ hhi, short* __restrict__ hlo) {
  const int row = blockIdx.x, t = threadIdx.x;
  float4* hp = (float4*)(h + (size_t)row * N_D);
  const float4* dp = (const float4*)(dlt + (size_t)row * N_D);
  const float4 a = hp[t], d = dp[t];
  const float v0 = a.x + d.x, v1 = a.y + d.y, v2 = a.z + d.z, v3 = a.w + d.w;
  float s = v0 + v1 + v2 + v3;
  float q = v0 * v0 + v1 * v1 + v2 * v2 + v3 * v3;
#pragma unroll
  for (int off = 32; off; off >>= 1) {
    s += __shfl_down(s, off);
    q += __shfl_down(q, off);
  }
  __shared__ float red[8];
  const int w = t >> 6;
  if ((t & 63) == 0) { red[w] = s; red[4 + w] = q; }
  __syncthreads();
  s = red[0] + red[1] + red[2] + red[3];
  q = red[4] + red[5] + red[6] + red[7];
  const float mean = s * (1.0f / N_D);
  const float var = q * (1.0f / N_D) - mean * mean;
  const float rstd = rsqrtf(var + 1e-5f);
  const float4 gv = ((const float4*)g)[t], bv = ((const float4*)bt)[t];
  float4 o;
  o.x = (v0 - mean) * rstd * gv.x + bv.x;
  o.y = (v1 - mean) * rstd * gv.y + bv.y;
  o.z = (v2 - mean) * rstd * gv.z + bv.z;
  o.w = (v3 - mean) * rstd * gv.w + bv.w;
  hp[t] = o;
  if (EB) {
    float v[4] = {o.x, o.y, o.z, o.w};
    short4v hi, lo;
    hilo4(v, hi, lo);
    *(short4v*)(hhi + (size_t)row * N_D + t * 4) = hi;
    *(short4v*)(hlo + (size_t)row * N_D + t * 4) = lo;
  }
}

// ---------------------------------------------------------------------------
__global__ void zero_kernel(float* __restrict__ p) { *p = 0.f; }

__global__ __launch_bounds__(64) void loss_kernel(
    const float* __restrict__ logits, const int* __restrict__ x,
    float* __restrict__ logp, float* __restrict__ loss) {
  const int row = blockIdx.x;
  const int lane = threadIdx.x;
  const float a = logits[(size_t)row * N_V + lane];
  const float c = logits[(size_t)row * N_V + 64 + lane];
  float m = fmaxf(a, c);
#pragma unroll
  for (int off = 32; off; off >>= 1) m = fmaxf(m, __shfl_xor(m, off));
  float e = __expf(a - m) + __expf(c - m);
#pragma unroll
  for (int off = 32; off; off >>= 1) e += __shfl_xor(e, off);
  const float lse = m + __logf(e);
  logp[(size_t)row * N_V + lane] = a - lse;
  logp[(size_t)row * N_V + 64 + lane] = c - lse;
  if (lane == 0) {
    const int tg = x[row];
    const float lp = logits[(size_t)row * N_V + tg] - lse;
    atomicAdd(loss, -lp * (1.0f / N_S));
  }
}

// ---------------------------------------------------------------------------
extern "C" void kernel_launch(void* const* d_in, const int* in_sizes, int n_in,
                              void* d_out, int out_size, void* d_ws, size_t ws_size,
                              hipStream_t stream) {
  const int*   x       = (const int*)d_in[0];
  const float* af_emb  = (const float*)d_in[1];
  const float* tok_emb = (const float*)d_in[2];
  const float* pos_emb = (const float*)d_in[3];
  const float* proj_w  = (const float*)d_in[4];
  const float* proj_b  = (const float*)d_in[5];
  const float* sa_wq   = (const float*)d_in[6];
  const float* sa_wk   = (const float*)d_in[7];
  const float* sa_wv   = (const float*)d_in[8];
  const float* sa_wo   = (const float*)d_in[9];
  const float* ca_wq   = (const float*)d_in[10];
  const float* ca_wk   = (const float*)d_in[11];
  const float* ca_wv   = (const float*)d_in[12];
  const float* ca_wo   = (const float*)d_in[13];
  const float* ffn_w1  = (const float*)d_in[14];
  const float* ffn_b1  = (const float*)d_in[15];
  const float* ffn_w2  = (const float*)d_in[16];
  const float* ffn_b2  = (const float*)d_in[17];
  const float* ln1_g   = (const float*)d_in[18];
  const float* ln1_b   = (const float*)d_in[19];
  const float* ln2_g   = (const float*)d_in[20];
  const float* ln2_b   = (const float*)d_in[21];
  const float* ln3_g   = (const float*)d_in[22];
  const float* ln3_b   = (const float*)d_in[23];
  const float* out_w   = (const float*)d_in[24];
  const float* out_b   = (const float*)d_in[25];

  const size_t nH   = (size_t)N_B * N_S * N_D;    // 6,553,600
  const size_t nMem = (size_t)N_B * N_M * N_D;    // 8,388,608
  const size_t nFfn = (size_t)N_B * N_S * N_F;    // 13,107,200
  const size_t nAf  = (size_t)N_B * N_M * N_DEMB; // 3,145,728
  const size_t nW   = 12582912;                   // per-layer Wt slots (elems)
  const size_t nSh  = nH + (size_t)N_B * N_M * 2048;  // 23,330,816 (shared f32)

  float* logp  = (float*)d_out;
  float* lossp = logp + (size_t)N_B * N_S * N_V;
  const dim3 blk(256);

  // ---- fast-path workspace layout ----
  const size_t fast_bytes = 4 * (2 * nH + nSh) +
                            2 * 2 * (2 * nH + nMem + nFfn + nAf + nW);
  if (ws_size >= fast_bytes) {
    char* p = (char*)d_ws;
    float* h    = (float*)p; p += nH * 4;
    float* ob   = (float*)p; p += nH * 4;
    float* shrd = (float*)p; p += nSh * 4;
    short* hhi   = (short*)p; p += nH * 2;
    short* hlo   = (short*)p; p += nH * 2;
    short* aobhi = (short*)p; p += nH * 2;
    short* aoblo = (short*)p; p += nH * 2;
    short* memhi = (short*)p; p += nMem * 2;
    short* memlo = (short*)p; p += nMem * 2;
    short* ffnhi = (short*)p; p += nFfn * 2;
    short* ffnlo = (short*)p; p += nFfn * 2;
    short* afhi  = (short*)p; p += nAf * 2;
    short* aflo  = (short*)p; p += nAf * 2;
    short* whi   = (short*)p; p += nW * 2;
    short* wlo   = (short*)p; p += nW * 2;
    // overlapping scratch (disjoint liveness): SA qkv vs CA q + kv vs logits
    float* qkv  = shrd;            // [6400][3072]
    float* caq  = shrd;            // [6400][1024]
    float* cakv = shrd + nH;       // [8192][2048]
    float* logits = shrd;          // [6400][128]

    const dim3 gS(50, 8);      // [6400][1024]
    const dim3 gQKV(50, 24);   // [6400][3072]
    const dim3 gM(64, 8);      // [8192][1024]
    const dim3 gKV(64, 16);    // [8192][2048]
    const dim3 gF(50, 16);     // [6400][2048]
    const dim3 gAttn(7, N_H, N_B);
    const long s1 = 1048576, sF1 = 8388608, sF2 = 10485760;

    embed_kernel<1><<<N_B * N_S, blk, 0, stream>>>(x, tok_emb, pos_emb, h, hhi, hlo);
    aconv<<<(int)(nAf / 1024), blk, 0, stream>>>(af_emb, afhi, aflo);
    wconv_one<<<6 * 16, blk, 0, stream>>>(proj_w, whi, wlo, N_DEMB, N_D);
    gemm_bf<0, 1, 1><<<gM, blk, 0, stream>>>(afhi, aflo, whi, wlo, proj_b,
                                             nullptr, memhi, memlo, N_DEMB, N_D);

    for (int l = 0; l < N_L; ++l) {
      const size_t wo = (size_t)l * N_D * N_D;
      const size_t fo = (size_t)l * N_D * N_F;
      wconv_layer<<<3072, blk, 0, stream>>>(
          sa_wq + wo, sa_wk + wo, sa_wv + wo, sa_wo + wo,
          ca_wq + wo, ca_wk + wo, ca_wv + wo, ca_wo + wo,
          ffn_w1 + fo, ffn_w2 + fo, whi, wlo);
      // ---- self attention (fused QKV: slots 0,1,2 = [3072][1024] B^T) ----
      gemm_bf<0, 0, 0><<<gQKV, blk, 0, stream>>>(hhi, hlo, whi, wlo,
                                                 nullptr, qkv, nullptr, nullptr,
                                                 N_D, 3072);
      attn_kernel<true, 1><<<gAttn, blk, 0, stream>>>(
          qkv, qkv + 1024, qkv + 2048, x, nullptr, aobhi, aoblo, N_S, 3072, 3072);
      gemm_bf<0, 0, 0><<<gS, blk, 0, stream>>>(aobhi, aoblo, whi + 3 * s1, wlo + 3 * s1,
                                               nullptr, ob, nullptr, nullptr, N_D, N_D);
      resln_kernel<1><<<N_B * N_S, blk, 0, stream>>>(h, ob, ln1_g + l * N_D,
                                                     ln1_b + l * N_D, hhi, hlo);
      // ---- cross attention (fused KV: slots 5,6 = [2048][1024] B^T) ----
      gemm_bf<0, 0, 0><<<gS, blk, 0, stream>>>(hhi, hlo, whi + 4 * s1, wlo + 4 * s1,
                                               nullptr, caq, nullptr, nullptr, N_D, N_D);
      gemm_bf<0, 0, 0><<<gKV, blk, 0, stream>>>(memhi, memlo, whi + 5 * s1, wlo + 5 * s1,
                                                nullptr, cakv, nullptr, nullptr,
                                                N_D, 2048);
      attn_kernel<false, 1><<<gAttn, blk, 0, stream>>>(
          caq, cakv, cakv + 1024, nullptr, nullptr, aobhi, aoblo, N_M, 1024, 2048);
      gemm_bf<0, 0, 0><<<gS, blk, 0, stream>>>(aobhi, aoblo, whi + 7 * s1, wlo + 7 * s1,
                                               nullptr, ob, nullptr, nullptr, N_D, N_D);
      resln_kernel<1><<<N_B * N_S, blk, 0, stream>>>(h, ob, ln2_g + l * N_D,
                                                     ln2_b + l * N_D, hhi, hlo);
      // ---- FFN ----
      gemm_bf<1, 1, 1><<<gF, blk, 0, stream>>>(hhi, hlo, whi + sF1, wlo + sF1,
                                               ffn_b1 + l * N_F, nullptr, ffnhi, ffnlo,
                                               N_D, N_F);
      gemm_bf<0, 1, 0><<<gS, blk, 0, stream>>>(ffnhi, ffnlo, whi + sF2, wlo + sF2,
                                               ffn_b2 + l * N_D, ob, nullptr, nullptr,
                                               N_F, N_D);
      resln_kernel<1><<<N_B * N_S, blk, 0, stream>>>(h, ob, ln3_g + l * N_D,
                                                     ln3_b + l * N_D, hhi, hlo);
    }

    gemm64<0, true><<<dim3(100, 2), blk, 0, stream>>>(h, out_w, out_b, logits,
                                                      N_B * N_S, N_V, N_D);
    zero_kernel<<<1, 1, 0, stream>>>(lossp);
    loss_kernel<<<N_B * N_S, 64, 0, stream>>>(logits, x, logp, lossp);
    return;
  }

  // ---- fallback: fp32 vector path ----
  {
    float* ws = (float*)d_ws;
    float* h   = ws;
    float* mem = h + nH;
    float* qb  = mem + nMem;
    float* kb  = qb + nH;
    float* vb  = kb + nMem;
    float* aob = vb + nMem;
    float* ob  = aob + nH;
    float* ffn = qb;
    float* logits = qb;

    const dim3 gS(50, 8), gM(64, 8), gF(50, 16);
    const dim3 gAttn(7, N_H, N_B);

    embed_kernel<0><<<N_B * N_S, blk, 0, stream>>>(x, tok_emb, pos_emb, h, nullptr, nullptr);
    gemm128<0, true><<<gM, blk, 0, stream>>>(af_emb, proj_w, proj_b, mem,
                                             N_B * N_M, N_D, N_DEMB);
    for (int l = 0; l < N_L; ++l) {
      const size_t wo = (size_t)l * N_D * N_D;
      gemm128<0, false><<<gS, blk, 0, stream>>>(h, sa_wq + wo, nullptr, qb, N_B * N_S, N_D, N_D);
      gemm128<0, false><<<gS, blk, 0, stream>>>(h, sa_wk + wo, nullptr, kb, N_B * N_S, N_D, N_D);
      gemm128<0, false><<<gS, blk, 0, stream>>>(h, sa_wv + wo, nullptr, vb, N_B * N_S, N_D, N_D);
      attn_kernel<true, 0><<<gAttn, blk, 0, stream>>>(qb, kb, vb, x, aob, nullptr, nullptr,
                                                      N_S, N_D, N_D);
      gemm128<0, false><<<gS, blk, 0, stream>>>(aob, sa_wo + wo, nullptr, ob, N_B * N_S, N_D, N_D);
      resln_kernel<0><<<N_B * N_S, blk, 0, stream>>>(h, ob, ln1_g + l * N_D, ln1_b + l * N_D,
                                                     nullptr, nullptr);
      gemm128<0, false><<<gS, blk, 0, stream>>>(h, ca_wq + wo, nullptr, qb, N_B * N_S, N_D, N_D);
      gemm128<0, false><<<gM, blk, 0, stream>>>(mem, ca_wk + wo, nullptr, kb, N_B * N_M, N_D, N_D);
      gemm128<0, false><<<gM, blk, 0, stream>>>(mem, ca_wv + wo, nullptr, vb, N_B * N_M, N_D, N_D);
      attn_kernel<false, 0><<<gAttn, blk, 0, stream>>>(qb, kb, vb, nullptr, aob, nullptr, nullptr,
                                                       N_M, N_D, N_D);
      gemm128<0, false><<<gS, blk, 0, stream>>>(aob, ca_wo + wo, nullptr, ob, N_B * N_S, N_D, N_D);
      resln_kernel<0><<<N_B * N_S, blk, 0, stream>>>(h, ob, ln2_g + l * N_D, ln2_b + l * N_D,
                                                     nullptr, nullptr);
      gemm128<1, true><<<gF, blk, 0, stream>>>(h, ffn_w1 + (size_t)l * N_D * N_F,
                                               ffn_b1 + l * N_F, ffn, N_B * N_S, N_F, N_D);
      gemm128<0, true><<<gS, blk, 0, stream>>>(ffn, ffn_w2 + (size_t)l * N_F * N_D,
                                               ffn_b2 + l * N_D, ob, N_B * N_S, N_D, N_F);
      resln_kernel<0><<<N_B * N_S, blk, 0, stream>>>(h, ob, ln3_g + l * N_D, ln3_b + l * N_D,
                                                     nullptr, nullptr);
    }
    gemm64<0, true><<<dim3(100, 2), blk, 0, stream>>>(h, out_w, out_b, logits,
                                                      N_B * N_S, N_V, N_D);
    zero_kernel<<<1, 1, 0, stream>>>(lossp);
    loss_kernel<<<N_B * N_S, 64, 0, stream>>>(logits, x, logp, lossp);
  }
}